// Round 1
// baseline (891.486 us; speedup 1.0000x reference)
//
#include <hip/hip_runtime.h>

#define NN 50000
#define NE 800000
#define D 128

// ---------------- CSR build ----------------

__global__ void k_hist(const int* __restrict__ dst, int* __restrict__ cnt, int e) {
  int i = blockIdx.x * blockDim.x + threadIdx.x;
  if (i < e) atomicAdd(&cnt[dst[i]], 1);
}

__global__ __launch_bounds__(1024) void k_scan(const int* __restrict__ cnt,
                                               int* __restrict__ row_start, int n) {
  __shared__ int wsum[16];
  __shared__ int carry_s;
  int t = threadIdx.x;
  int lane = t & 63, wid = t >> 6;
  if (t == 0) carry_s = 0;
  __syncthreads();
  for (int base = 0; base < n; base += 1024) {
    int i = base + t;
    int v = (i < n) ? cnt[i] : 0;
    int x = v;
    #pragma unroll
    for (int off = 1; off < 64; off <<= 1) {
      int y = __shfl_up(x, off, 64);
      if (lane >= off) x += y;
    }
    if (lane == 63) wsum[wid] = x;
    __syncthreads();
    if (wid == 0) {
      int w = (lane < 16) ? wsum[lane] : 0;
      #pragma unroll
      for (int off = 1; off < 16; off <<= 1) {
        int y = __shfl_up(w, off, 64);
        if (lane >= off) w += y;
      }
      if (lane < 16) wsum[lane] = w;
    }
    __syncthreads();
    int waveoff = wid ? wsum[wid - 1] : 0;
    if (i < n) row_start[i] = carry_s + waveoff + (x - v);
    __syncthreads();
    if (t == 0) carry_s += wsum[15];
    __syncthreads();
  }
  if (t == 0) row_start[n] = carry_s;
}

__global__ void k_scatter(const int* __restrict__ src, const int* __restrict__ dst,
                          const int* __restrict__ row_start, int* __restrict__ cursor,
                          int* __restrict__ csr_src, int e) {
  int i = blockIdx.x * blockDim.x + threadIdx.x;
  if (i < e) {
    int d = dst[i];
    int pos = atomicAdd(&cursor[d], 1);
    csr_src[row_start[d] + pos] = src[i];
  }
}

// ---------------- Aggregation: one wave per node ----------------
// AGGR: 0 = sum, 1 = max, 2 = mean

template <int AGGR>
__global__ __launch_bounds__(256) void k_aggregate(const float* __restrict__ h,
                                                   const int* __restrict__ csr_src,
                                                   const int* __restrict__ row_start,
                                                   float* __restrict__ agg, int n) {
  int lane = threadIdx.x & 63;
  int node = blockIdx.x * 4 + (threadIdx.x >> 6);
  if (node >= n) return;
  const float2* __restrict__ hp = (const float2*)h;
  int s = row_start[node], e = row_start[node + 1];
  float2 a0, a1;
  if (AGGR == 1) { a0 = make_float2(-INFINITY, -INFINITY); a1 = a0; }
  else           { a0 = make_float2(0.f, 0.f);             a1 = a0; }
  int j = s;
  for (; j + 1 < e; j += 2) {
    int s0 = csr_src[j], s1 = csr_src[j + 1];
    float2 v0 = hp[(size_t)s0 * 64 + lane];
    float2 v1 = hp[(size_t)s1 * 64 + lane];
    if (AGGR == 1) {
      a0.x = fmaxf(a0.x, v0.x); a0.y = fmaxf(a0.y, v0.y);
      a1.x = fmaxf(a1.x, v1.x); a1.y = fmaxf(a1.y, v1.y);
    } else {
      a0.x += v0.x; a0.y += v0.y;
      a1.x += v1.x; a1.y += v1.y;
    }
  }
  if (j < e) {
    int s0 = csr_src[j];
    float2 v0 = hp[(size_t)s0 * 64 + lane];
    if (AGGR == 1) { a0.x = fmaxf(a0.x, v0.x); a0.y = fmaxf(a0.y, v0.y); }
    else           { a0.x += v0.x; a0.y += v0.y; }
  }
  float2 r;
  if (AGGR == 1) {
    r.x = fmaxf(a0.x, a1.x); r.y = fmaxf(a0.y, a1.y);
    if (e == s) { r.x = 0.f; r.y = 0.f; }   // empty segment -> 0 (PyG fill)
  } else {
    r.x = a0.x + a1.x; r.y = a0.y + a1.y;
    if (AGGR == 2) {
      float inv = 1.0f / fmaxf((float)(e - s), 1.0f);
      r.x *= inv; r.y *= inv;
    }
  }
  ((float2*)agg)[(size_t)node * 64 + lane] = r;
}

// ---------------- Fused GEMM: out = relu(A1@W1 [+ A2@W2] + bias) ----------------
// A: [M,128], W: [128,128] row-major (k,c), out: [M,128]. out may alias A1
// (each block reads only its own BM rows, all before its writes).

#define BM 64
#define BK 32

__global__ __launch_bounds__(256) void k_gemm(const float* __restrict__ A1,
                                              const float* __restrict__ W1,
                                              const float* __restrict__ A2,
                                              const float* __restrict__ W2,
                                              const float* __restrict__ bias,
                                              float* __restrict__ out,
                                              int M, int has2) {
  __shared__ float As[BM][BK + 4];   // stride 36 floats: 16B-aligned rows, no bank conflict
  __shared__ float Ws[BK][D];
  int t = threadIdx.x;
  int tx = t & 15;        // 16 col groups * 8 cols
  int ty = t >> 4;        // 16 row groups * 4 rows
  int row0 = blockIdx.x * BM;

  float acc[4][8];
  #pragma unroll
  for (int i = 0; i < 4; ++i)
    #pragma unroll
    for (int j = 0; j < 8; ++j) acc[i][j] = 0.f;

  int nmat = has2 ? 2 : 1;
  for (int mat = 0; mat < nmat; ++mat) {
    const float* __restrict__ A = mat ? A2 : A1;
    const float* __restrict__ W = mat ? W2 : W1;
    for (int k0 = 0; k0 < D; k0 += BK) {
      __syncthreads();
      // stage A tile: 64 rows x 32 k
      {
        int r = t >> 3, c = (t & 7) * 4;
        #pragma unroll
        for (int rr = 0; rr < BM; rr += 32) {
          int grow = row0 + r + rr;
          float4 v = make_float4(0.f, 0.f, 0.f, 0.f);
          if (grow < M) v = *(const float4*)&A[(size_t)grow * D + k0 + c];
          *(float4*)&As[r + rr][c] = v;
        }
      }
      // stage W tile: 32 k x 128 c
      {
        int kr = t >> 5, wc = (t & 31) * 4;
        #pragma unroll
        for (int kk = 0; kk < BK; kk += 8) {
          float4 v = *(const float4*)&W[(size_t)(k0 + kr + kk) * D + wc];
          *(float4*)&Ws[kr + kk][wc] = v;
        }
      }
      __syncthreads();
      #pragma unroll 8
      for (int kk = 0; kk < BK; ++kk) {
        float a[4];
        #pragma unroll
        for (int i = 0; i < 4; ++i) a[i] = As[ty * 4 + i][kk];
        float4 b0 = *(const float4*)&Ws[kk][tx * 8];
        float4 b1 = *(const float4*)&Ws[kk][tx * 8 + 4];
        float bb[8] = {b0.x, b0.y, b0.z, b0.w, b1.x, b1.y, b1.z, b1.w};
        #pragma unroll
        for (int i = 0; i < 4; ++i)
          #pragma unroll
          for (int j = 0; j < 8; ++j)
            acc[i][j] = fmaf(a[i], bb[j], acc[i][j]);
      }
    }
  }

  float4 bb0 = *(const float4*)&bias[tx * 8];
  float4 bb1 = *(const float4*)&bias[tx * 8 + 4];
  float bj[8] = {bb0.x, bb0.y, bb0.z, bb0.w, bb1.x, bb1.y, bb1.z, bb1.w};
  #pragma unroll
  for (int i = 0; i < 4; ++i) {
    int grow = row0 + ty * 4 + i;
    if (grow < M) {
      float o[8];
      #pragma unroll
      for (int j = 0; j < 8; ++j) o[j] = fmaxf(acc[i][j] + bj[j], 0.f);
      float4 s0 = make_float4(o[0], o[1], o[2], o[3]);
      float4 s1 = make_float4(o[4], o[5], o[6], o[7]);
      *(float4*)&out[(size_t)grow * D + tx * 8]     = s0;
      *(float4*)&out[(size_t)grow * D + tx * 8 + 4] = s1;
    }
  }
}

// ---------------- Head: out[n,2] = h @ w2 + b2 ----------------

__global__ __launch_bounds__(256) void k_head(const float* __restrict__ h,
                                              const float* __restrict__ w2,
                                              const float* __restrict__ b2,
                                              float* __restrict__ out, int n) {
  int lane = threadIdx.x & 63;
  int node = blockIdx.x * 4 + (threadIdx.x >> 6);
  if (node >= n) return;
  float2 v = ((const float2*)h)[(size_t)node * 64 + lane];
  float4 w = *(const float4*)&w2[lane * 4];   // rows 2*lane, 2*lane+1 of [128,2]
  float p0 = v.x * w.x + v.y * w.z;
  float p1 = v.x * w.y + v.y * w.w;
  #pragma unroll
  for (int off = 32; off; off >>= 1) {
    p0 += __shfl_xor(p0, off, 64);
    p1 += __shfl_xor(p1, off, 64);
  }
  if (lane == 0)
    ((float2*)out)[node] = make_float2(p0 + b2[0], p1 + b2[1]);
}

// ---------------- Launch ----------------

extern "C" void kernel_launch(void* const* d_in, const int* in_sizes, int n_in,
                              void* d_out, int out_size, void* d_ws, size_t ws_size,
                              hipStream_t stream) {
  const float* x   = (const float*)d_in[0];
  const int*   ei  = (const int*)d_in[1];
  const float* w_l = (const float*)d_in[2];
  const float* b_l = (const float*)d_in[3];
  const float* w_r = (const float*)d_in[4];
  const float* w1  = (const float*)d_in[5];
  const float* b1  = (const float*)d_in[6];
  const float* w2  = (const float*)d_in[7];
  const float* b2  = (const float*)d_in[8];
  float* out = (float*)d_out;

  const int* src = ei;        // edge_index[0]
  const int* dst = ei + NE;   // edge_index[1]

  char* ws = (char*)d_ws;
  size_t SZ = (size_t)NN * D * sizeof(float);
  float* bufA = (float*)ws;
  float* bufB = (float*)(ws + SZ);
  int* csr_src   = (int*)(ws + 2 * SZ);
  int* row_start = (int*)(ws + 2 * SZ + (size_t)NE * sizeof(int));
  int* cnt       = row_start + NN + 2;

  hipMemsetAsync(cnt, 0, NN * sizeof(int), stream);
  k_hist<<<(NE + 255) / 256, 256, 0, stream>>>(dst, cnt, NE);
  k_scan<<<1, 1024, 0, stream>>>(cnt, row_start, NN);
  hipMemsetAsync(cnt, 0, NN * sizeof(int), stream);
  k_scatter<<<(NE + 255) / 256, 256, 0, stream>>>(src, dst, row_start, cnt, csr_src, NE);

  const int agg_grid  = (NN + 3) / 4;
  const int gemm_grid = (NN + BM - 1) / BM;

  const float* h = x;
  float* bufs[2] = {bufA, bufB};
  for (int i = 0; i < 6; ++i) {
    float* aggb = bufs[i & 1];
    switch (i % 3) {
      case 0: k_aggregate<0><<<agg_grid, 256, 0, stream>>>(h, csr_src, row_start, aggb, NN); break;
      case 1: k_aggregate<1><<<agg_grid, 256, 0, stream>>>(h, csr_src, row_start, aggb, NN); break;
      case 2: k_aggregate<2><<<agg_grid, 256, 0, stream>>>(h, csr_src, row_start, aggb, NN); break;
    }
    k_gemm<<<gemm_grid, 256, 0, stream>>>(aggb, w_l + (size_t)i * D * D,
                                          h,    w_r + (size_t)i * D * D,
                                          b_l + (size_t)i * D, aggb, NN, 1);
    h = aggb;
  }
  // h == bufB after layer 5
  k_gemm<<<gemm_grid, 256, 0, stream>>>(h, w1, nullptr, nullptr, b1, bufA, NN, 0);
  k_head<<<agg_grid, 256, 0, stream>>>(bufA, w2, b2, out, NN);
}

// Round 2
// 689.481 us; speedup vs baseline: 1.2930x; 1.2930x over previous
//
#include <hip/hip_runtime.h>

#define NN 50000
#define NE 800000
#define D 128

typedef unsigned short ushort_t;
typedef __attribute__((ext_vector_type(8))) short short8;
typedef __attribute__((ext_vector_type(4))) float f32x4;

__device__ __forceinline__ void split2(float f, unsigned& hi_bits_u, float& lo_f) {
  unsigned u = __float_as_uint(f);
  hi_bits_u = u;                                  // top 16 bits = bf16 hi (truncated)
  lo_f = f - __uint_as_float(u & 0xffff0000u);    // exact residual
}

// ---------------- CSR build ----------------

__global__ void k_hist(const int* __restrict__ dst, int* __restrict__ cnt, int e) {
  int i = blockIdx.x * blockDim.x + threadIdx.x;
  if (i < e) atomicAdd(&cnt[dst[i]], 1);
}

__global__ __launch_bounds__(1024) void k_scan(const int* __restrict__ cnt,
                                               int* __restrict__ row_start, int n) {
  __shared__ int wsum[16];
  __shared__ int carry_s;
  int t = threadIdx.x;
  int lane = t & 63, wid = t >> 6;
  if (t == 0) carry_s = 0;
  __syncthreads();
  for (int base = 0; base < n; base += 1024) {
    int i = base + t;
    int v = (i < n) ? cnt[i] : 0;
    int x = v;
    #pragma unroll
    for (int off = 1; off < 64; off <<= 1) {
      int y = __shfl_up(x, off, 64);
      if (lane >= off) x += y;
    }
    if (lane == 63) wsum[wid] = x;
    __syncthreads();
    if (wid == 0) {
      int w = (lane < 16) ? wsum[lane] : 0;
      #pragma unroll
      for (int off = 1; off < 16; off <<= 1) {
        int y = __shfl_up(w, off, 64);
        if (lane >= off) w += y;
      }
      if (lane < 16) wsum[lane] = w;
    }
    __syncthreads();
    int waveoff = wid ? wsum[wid - 1] : 0;
    if (i < n) row_start[i] = carry_s + waveoff + (x - v);
    __syncthreads();
    if (t == 0) carry_s += wsum[15];
    __syncthreads();
  }
  if (t == 0) row_start[n] = carry_s;
}

__global__ void k_scatter(const int* __restrict__ src, const int* __restrict__ dst,
                          const int* __restrict__ row_start, int* __restrict__ cursor,
                          int* __restrict__ csr_src, int e) {
  int i = blockIdx.x * blockDim.x + threadIdx.x;
  if (i < e) {
    int d = dst[i];
    int pos = atomicAdd(&cursor[d], 1);
    csr_src[row_start[d] + pos] = src[i];
  }
}

// ---------------- Weight pre-split: fp32 [mat][k][c] -> bf16 hi/lo planes ----------------
// Plane layout (per mat, 16384 elems): [kt=k>>5][c][k&31]  (tiled for coalesced staging)

__global__ void k_wsplit(const float* __restrict__ W, ushort_t* __restrict__ hi,
                         ushort_t* __restrict__ lo, int total) {
  int idx = blockIdx.x * 256 + threadIdx.x;
  if (idx >= total) return;
  int mat = idx >> 14, rem = idx & 16383;
  int k = rem >> 7, c = rem & 127;
  float f = W[idx];
  unsigned hu; float lf;
  split2(f, hu, lf);
  size_t dst = ((size_t)mat << 14) + (size_t)(k >> 5) * 4096 + c * 32 + (k & 31);
  hi[dst] = (ushort_t)(hu >> 16);
  lo[dst] = (ushort_t)(__float_as_uint(lf) >> 16);
}

// ---------------- Aggregation: one wave per node, float4 half-wave ----------------
// AGGR: 0 = sum, 1 = max, 2 = mean

__device__ __forceinline__ float4 op_add(float4 a, float4 v) {
  a.x += v.x; a.y += v.y; a.z += v.z; a.w += v.w; return a;
}
__device__ __forceinline__ float4 op_max(float4 a, float4 v) {
  a.x = fmaxf(a.x, v.x); a.y = fmaxf(a.y, v.y);
  a.z = fmaxf(a.z, v.z); a.w = fmaxf(a.w, v.w); return a;
}

template <int AGGR>
__global__ __launch_bounds__(256) void k_aggregate(const float* __restrict__ h,
                                                   const int* __restrict__ csr_src,
                                                   const int* __restrict__ row_start,
                                                   float* __restrict__ agg, int n) {
  int lane = threadIdx.x & 63;
  int node = blockIdx.x * 4 + (threadIdx.x >> 6);
  if (node >= n) return;
  int half = lane >> 5, c = lane & 31;
  const float4* __restrict__ hp = (const float4*)h;
  int s = row_start[node], e = row_start[node + 1];
  float4 a0, a1;
  if (AGGR == 1) a0 = make_float4(-INFINITY, -INFINITY, -INFINITY, -INFINITY);
  else           a0 = make_float4(0.f, 0.f, 0.f, 0.f);
  a1 = a0;
  int j = s + half;
  for (; j + 2 < e; j += 4) {
    int i0 = csr_src[j], i1 = csr_src[j + 2];
    float4 v0 = hp[(size_t)i0 * 32 + c];
    float4 v1 = hp[(size_t)i1 * 32 + c];
    if (AGGR == 1) { a0 = op_max(a0, v0); a1 = op_max(a1, v1); }
    else           { a0 = op_add(a0, v0); a1 = op_add(a1, v1); }
  }
  for (; j < e; j += 2) {
    float4 v0 = hp[(size_t)csr_src[j] * 32 + c];
    if (AGGR == 1) a0 = op_max(a0, v0); else a0 = op_add(a0, v0);
  }
  float4 r = (AGGR == 1) ? op_max(a0, a1) : op_add(a0, a1);
  // combine the two halves (lane L <-> L+32)
  float4 o;
  o.x = __shfl_xor(r.x, 32, 64);
  o.y = __shfl_xor(r.y, 32, 64);
  o.z = __shfl_xor(r.z, 32, 64);
  o.w = __shfl_xor(r.w, 32, 64);
  r = (AGGR == 1) ? op_max(r, o) : op_add(r, o);
  if (half == 0) {
    if (AGGR == 1) {
      if (e == s) r = make_float4(0.f, 0.f, 0.f, 0.f);  // empty -> 0 (PyG fill)
    } else if (AGGR == 2) {
      float inv = 1.0f / fmaxf((float)(e - s), 1.0f);
      r.x *= inv; r.y *= inv; r.z *= inv; r.w *= inv;
    }
    ((float4*)agg)[(size_t)node * 32 + c] = r;
  }
}

// ---------------- MFMA GEMM (bf16x3 split): out = relu(A1@W1 [+ A2@W2] + bias) ----------------
// A: [M,128] fp32. W planes: pre-split bf16 hi/lo, layout [kt][c][32] per mat.
// out may alias A1 (each block reads only its own rows, all before its writes).

#define GBM 128

__global__ __launch_bounds__(256) void k_gemm(
    const float* __restrict__ A1, const ushort_t* __restrict__ Wh1, const ushort_t* __restrict__ Wl1,
    const float* __restrict__ A2, const ushort_t* __restrict__ Wh2, const ushort_t* __restrict__ Wl2,
    const float* __restrict__ bias, float* __restrict__ out, int M, int has2) {
  // padded LDS: row stride 40 ushorts (80 B) -> 16B-aligned, ~2-way max bank aliasing
  __shared__ ushort_t Ah[128 * 40];
  __shared__ ushort_t Al[128 * 40];
  __shared__ ushort_t Bh[128 * 40];
  __shared__ ushort_t Bl[128 * 40];
  int t = threadIdx.x;
  int lane = t & 63, wid = t >> 6;
  int wr = wid >> 1, wc = wid & 1;      // 2x2 wave grid, wave tile 64x64
  int l15 = lane & 15, kg = lane >> 4;
  int row0 = blockIdx.x * GBM;

  f32x4 acc[4][4] = {};

  int nmat = has2 ? 2 : 1;
  for (int mat = 0; mat < nmat; ++mat) {
    const float* __restrict__ A = mat ? A2 : A1;
    const ushort_t* __restrict__ Wh = mat ? Wh2 : Wh1;
    const ushort_t* __restrict__ Wl = mat ? Wl2 : Wl1;
    for (int kt = 0; kt < 4; ++kt) {
      __syncthreads();
      // --- stage A tile (128 rows x 32 k), split fp32 -> bf16 hi/lo
      {
        int r = t >> 3, cq = t & 7;      // 32 rows/chunk, 8 float4 per row
        #pragma unroll
        for (int rr = 0; rr < 4; ++rr) {
          int row = r + rr * 32;
          int grow = row0 + row;
          float4 v = make_float4(0.f, 0.f, 0.f, 0.f);
          if (grow < M) v = *(const float4*)&A[(size_t)grow * D + kt * 32 + cq * 4];
          unsigned u0 = __float_as_uint(v.x), u1 = __float_as_uint(v.y);
          unsigned u2 = __float_as_uint(v.z), u3 = __float_as_uint(v.w);
          unsigned h01 = (u0 >> 16) | (u1 & 0xffff0000u);
          unsigned h23 = (u2 >> 16) | (u3 & 0xffff0000u);
          float f0 = v.x - __uint_as_float(u0 & 0xffff0000u);
          float f1 = v.y - __uint_as_float(u1 & 0xffff0000u);
          float f2 = v.z - __uint_as_float(u2 & 0xffff0000u);
          float f3 = v.w - __uint_as_float(u3 & 0xffff0000u);
          unsigned l01 = (__float_as_uint(f0) >> 16) | (__float_as_uint(f1) & 0xffff0000u);
          unsigned l23 = (__float_as_uint(f2) >> 16) | (__float_as_uint(f3) & 0xffff0000u);
          *(uint2*)&Ah[row * 40 + cq * 4] = make_uint2(h01, h23);
          *(uint2*)&Al[row * 40 + cq * 4] = make_uint2(l01, l23);
        }
      }
      // --- stage W tile (128 c x 32 k) from pre-split planes (coalesced 32B/thread)
      {
        int c = t >> 1, q = t & 1;
        const ushort_t* sh = Wh + (size_t)kt * 4096 + t * 16;
        const ushort_t* sl = Wl + (size_t)kt * 4096 + t * 16;
        uint4 a0 = *(const uint4*)sh;
        uint4 a1 = *(const uint4*)(sh + 8);
        uint4 b0 = *(const uint4*)sl;
        uint4 b1 = *(const uint4*)(sl + 8);
        *(uint4*)&Bh[c * 40 + q * 16]     = a0;
        *(uint4*)&Bh[c * 40 + q * 16 + 8] = a1;
        *(uint4*)&Bl[c * 40 + q * 16]     = b0;
        *(uint4*)&Bl[c * 40 + q * 16 + 8] = b1;
      }
      __syncthreads();
      // --- fragments + MFMA
      short8 ah[4], al[4], bh[4], bl[4];
      #pragma unroll
      for (int m = 0; m < 4; ++m) {
        int row = wr * 64 + m * 16 + l15;
        ah[m] = *(const short8*)&Ah[row * 40 + kg * 8];
        al[m] = *(const short8*)&Al[row * 40 + kg * 8];
      }
      #pragma unroll
      for (int n = 0; n < 4; ++n) {
        int col = wc * 64 + n * 16 + l15;
        bh[n] = *(const short8*)&Bh[col * 40 + kg * 8];
        bl[n] = *(const short8*)&Bl[col * 40 + kg * 8];
      }
      #pragma unroll
      for (int m = 0; m < 4; ++m)
        #pragma unroll
        for (int n = 0; n < 4; ++n) {
          acc[m][n] = __builtin_amdgcn_mfma_f32_16x16x32_bf16(ah[m], bh[n], acc[m][n], 0, 0, 0);
          acc[m][n] = __builtin_amdgcn_mfma_f32_16x16x32_bf16(ah[m], bl[n], acc[m][n], 0, 0, 0);
          acc[m][n] = __builtin_amdgcn_mfma_f32_16x16x32_bf16(al[m], bh[n], acc[m][n], 0, 0, 0);
        }
    }
  }
  // --- epilogue: bias + relu, scalar stores (C/D: col=lane&15, row=(lane>>4)*4+reg)
  int crow = kg * 4;
  #pragma unroll
  for (int n = 0; n < 4; ++n) {
    int col = wc * 64 + n * 16 + l15;
    float b = bias[col];
    #pragma unroll
    for (int m = 0; m < 4; ++m) {
      int rbase = row0 + wr * 64 + m * 16 + crow;
      #pragma unroll
      for (int q = 0; q < 4; ++q) {
        int grow = rbase + q;
        if (grow < M) out[(size_t)grow * D + col] = fmaxf(acc[m][n][q] + b, 0.f);
      }
    }
  }
}

// ---------------- Head: out[n,2] = h @ w2 + b2 ----------------

__global__ __launch_bounds__(256) void k_head(const float* __restrict__ h,
                                              const float* __restrict__ w2,
                                              const float* __restrict__ b2,
                                              float* __restrict__ out, int n) {
  int lane = threadIdx.x & 63;
  int node = blockIdx.x * 4 + (threadIdx.x >> 6);
  if (node >= n) return;
  float2 v = ((const float2*)h)[(size_t)node * 64 + lane];
  float4 w = *(const float4*)&w2[lane * 4];
  float p0 = v.x * w.x + v.y * w.z;
  float p1 = v.x * w.y + v.y * w.w;
  #pragma unroll
  for (int off = 32; off; off >>= 1) {
    p0 += __shfl_xor(p0, off, 64);
    p1 += __shfl_xor(p1, off, 64);
  }
  if (lane == 0)
    ((float2*)out)[node] = make_float2(p0 + b2[0], p1 + b2[1]);
}

// ---------------- Launch ----------------

extern "C" void kernel_launch(void* const* d_in, const int* in_sizes, int n_in,
                              void* d_out, int out_size, void* d_ws, size_t ws_size,
                              hipStream_t stream) {
  const float* x   = (const float*)d_in[0];
  const int*   ei  = (const int*)d_in[1];
  const float* w_l = (const float*)d_in[2];
  const float* b_l = (const float*)d_in[3];
  const float* w_r = (const float*)d_in[4];
  const float* w1  = (const float*)d_in[5];
  const float* b1  = (const float*)d_in[6];
  const float* w2  = (const float*)d_in[7];
  const float* b2  = (const float*)d_in[8];
  float* out = (float*)d_out;

  const int* src = ei;        // edge_index[0]
  const int* dst = ei + NE;   // edge_index[1]

  char* ws = (char*)d_ws;
  size_t SZ = (size_t)NN * D * sizeof(float);
  float* bufA = (float*)ws;
  float* bufB = (float*)(ws + SZ);
  int* csr_src   = (int*)(ws + 2 * SZ);
  int* row_start = (int*)(ws + 2 * SZ + (size_t)NE * sizeof(int));
  int* cnt       = row_start + NN + 2;
  ushort_t* whi  = (ushort_t*)(cnt + NN + 2);
  ushort_t* wlo  = whi + 13 * 16384;

  // weight pre-split (13 matrices: 6x w_l, 6x w_r, 1x w1)
  k_wsplit<<<(6 * 16384 + 255) / 256, 256, 0, stream>>>(w_l, whi, wlo, 6 * 16384);
  k_wsplit<<<(6 * 16384 + 255) / 256, 256, 0, stream>>>(w_r, whi + 6 * 16384, wlo + 6 * 16384, 6 * 16384);
  k_wsplit<<<(16384 + 255) / 256, 256, 0, stream>>>(w1, whi + 12 * 16384, wlo + 12 * 16384, 16384);

  hipMemsetAsync(cnt, 0, NN * sizeof(int), stream);
  k_hist<<<(NE + 255) / 256, 256, 0, stream>>>(dst, cnt, NE);
  k_scan<<<1, 1024, 0, stream>>>(cnt, row_start, NN);
  hipMemsetAsync(cnt, 0, NN * sizeof(int), stream);
  k_scatter<<<(NE + 255) / 256, 256, 0, stream>>>(src, dst, row_start, cnt, csr_src, NE);

  const int agg_grid  = (NN + 3) / 4;
  const int gemm_grid = (NN + GBM - 1) / GBM;

  const float* h = x;
  float* bufs[2] = {bufA, bufB};
  for (int i = 0; i < 6; ++i) {
    float* aggb = bufs[i & 1];
    switch (i % 3) {
      case 0: k_aggregate<0><<<agg_grid, 256, 0, stream>>>(h, csr_src, row_start, aggb, NN); break;
      case 1: k_aggregate<1><<<agg_grid, 256, 0, stream>>>(h, csr_src, row_start, aggb, NN); break;
      case 2: k_aggregate<2><<<agg_grid, 256, 0, stream>>>(h, csr_src, row_start, aggb, NN); break;
    }
    k_gemm<<<gemm_grid, 256, 0, stream>>>(aggb, whi + (size_t)i * 16384, wlo + (size_t)i * 16384,
                                          h,    whi + (size_t)(6 + i) * 16384, wlo + (size_t)(6 + i) * 16384,
                                          b_l + (size_t)i * D, aggb, NN, 1);
    h = aggb;
  }
  // h == bufB after layer 5
  k_gemm<<<gemm_grid, 256, 0, stream>>>(h, whi + (size_t)12 * 16384, wlo + (size_t)12 * 16384,
                                        h, nullptr, nullptr, b1, bufA, NN, 0);
  k_head<<<agg_grid, 256, 0, stream>>>(bufA, w2, b2, out, NN);
}

// Round 3
// 644.495 us; speedup vs baseline: 1.3832x; 1.0698x over previous
//
#include <hip/hip_runtime.h>

#define NN 50000
#define NE 800000
#define D 128

typedef unsigned short ushort_t;
typedef __attribute__((ext_vector_type(8))) short short8;
typedef __attribute__((ext_vector_type(4))) float f32x4;

// ---------------- CSR build ----------------

__global__ void k_hist(const int* __restrict__ dst, int* __restrict__ cnt, int e) {
  int i = blockIdx.x * blockDim.x + threadIdx.x;
  if (i < e) atomicAdd(&cnt[dst[i]], 1);
}

// 1024 threads, 4 elems/thread/iter. Writes row_start AND cursor (= copy).
__global__ __launch_bounds__(1024) void k_scan(const int* __restrict__ cnt,
                                               int* __restrict__ row_start,
                                               int* __restrict__ cursor, int n) {
  __shared__ int wsum[16];
  __shared__ int carry_s;
  int t = threadIdx.x;
  int lane = t & 63, wid = t >> 6;
  if (t == 0) carry_s = 0;
  __syncthreads();
  for (int base = 0; base < n; base += 4096) {
    int i = base + t * 4;
    int4 v = make_int4(0, 0, 0, 0);
    if (i + 3 < n) v = *(const int4*)&cnt[i];
    else if (i < n) {
      v.x = cnt[i];
      if (i + 1 < n) v.y = cnt[i + 1];
      if (i + 2 < n) v.z = cnt[i + 2];
    }
    int tot = v.x + v.y + v.z + v.w;
    int x = tot;
    #pragma unroll
    for (int off = 1; off < 64; off <<= 1) {
      int y = __shfl_up(x, off, 64);
      if (lane >= off) x += y;
    }
    if (lane == 63) wsum[wid] = x;
    __syncthreads();
    if (wid == 0) {
      int w = (lane < 16) ? wsum[lane] : 0;
      #pragma unroll
      for (int off = 1; off < 16; off <<= 1) {
        int y = __shfl_up(w, off, 64);
        if (lane >= off) w += y;
      }
      if (lane < 16) wsum[lane] = w;
    }
    __syncthreads();
    int off0 = carry_s + (wid ? wsum[wid - 1] : 0) + (x - tot);
    int4 o;
    o.x = off0;
    o.y = off0 + v.x;
    o.z = off0 + v.x + v.y;
    o.w = off0 + v.x + v.y + v.z;
    if (i + 3 < n) {
      *(int4*)&row_start[i] = o;
      *(int4*)&cursor[i] = o;
    } else if (i < n) {
      row_start[i] = o.x; cursor[i] = o.x;
      if (i + 1 < n) { row_start[i + 1] = o.y; cursor[i + 1] = o.y; }
      if (i + 2 < n) { row_start[i + 2] = o.z; cursor[i + 2] = o.z; }
    }
    __syncthreads();
    if (t == 0) carry_s += wsum[15];
    __syncthreads();
  }
  if (t == 0) row_start[n] = carry_s;
}

// 4 edges per thread, independent atomic->write chains. NE % 4 == 0.
__global__ __launch_bounds__(256) void k_scatter(const int* __restrict__ src,
                                                 const int* __restrict__ dst,
                                                 int* __restrict__ cursor,
                                                 int* __restrict__ csr_src, int e) {
  int i = (blockIdx.x * 256 + threadIdx.x) * 4;
  if (i >= e) return;
  int4 s4 = *(const int4*)&src[i];
  int4 d4 = *(const int4*)&dst[i];
  int p0 = atomicAdd(&cursor[d4.x], 1);
  int p1 = atomicAdd(&cursor[d4.y], 1);
  int p2 = atomicAdd(&cursor[d4.z], 1);
  int p3 = atomicAdd(&cursor[d4.w], 1);
  csr_src[p0] = s4.x;
  csr_src[p1] = s4.y;
  csr_src[p2] = s4.z;
  csr_src[p3] = s4.w;
}

// ---------------- Weight pre-split: fp32 [mat][k][c] -> bf16 hi/lo planes ----------------
// Plane layout (per mat, 16384 elems): [kt=k>>5][c][k&31]

__global__ void k_wsplit(const float* __restrict__ W, ushort_t* __restrict__ hi,
                         ushort_t* __restrict__ lo, int total) {
  int idx = blockIdx.x * 256 + threadIdx.x;
  if (idx >= total) return;
  int mat = idx >> 14, rem = idx & 16383;
  int k = rem >> 7, c = rem & 127;
  float f = W[idx];
  unsigned u = __float_as_uint(f);
  float lf = f - __uint_as_float(u & 0xffff0000u);
  size_t dst = ((size_t)mat << 14) + (size_t)(k >> 5) * 4096 + c * 32 + (k & 31);
  hi[dst] = (ushort_t)(u >> 16);
  lo[dst] = (ushort_t)(__float_as_uint(lf) >> 16);
}

// ---------------- Aggregation: one wave per node, 16 lanes per edge ----------------
// AGGR: 0 = sum, 1 = max, 2 = mean
// Each lane owns 8 columns (2 float4 = 32B); 4 edge slots per wave; unroll 2
// -> 16 float4 loads in flight per wave.

__device__ __forceinline__ float4 op_add(float4 a, float4 v) {
  a.x += v.x; a.y += v.y; a.z += v.z; a.w += v.w; return a;
}
__device__ __forceinline__ float4 op_max(float4 a, float4 v) {
  a.x = fmaxf(a.x, v.x); a.y = fmaxf(a.y, v.y);
  a.z = fmaxf(a.z, v.z); a.w = fmaxf(a.w, v.w); return a;
}

template <int AGGR>
__global__ __launch_bounds__(256) void k_aggregate(const float* __restrict__ h,
                                                   const int* __restrict__ csr_src,
                                                   const int* __restrict__ row_start,
                                                   float* __restrict__ agg, int n) {
  int lane = threadIdx.x & 63;
  int node = blockIdx.x * 4 + (threadIdx.x >> 6);
  if (node >= n) return;
  int slot = lane >> 4, c = lane & 15;     // slot 0..3, lane owns float4s c*2, c*2+1
  const float4* __restrict__ hp = (const float4*)h;
  int s = row_start[node], e = row_start[node + 1];
  float4 init;
  if (AGGR == 1) init = make_float4(-INFINITY, -INFINITY, -INFINITY, -INFINITY);
  else           init = make_float4(0.f, 0.f, 0.f, 0.f);
  float4 a0x = init, a0y = init, a1x = init, a1y = init;
  int j = s + slot;
  for (; j + 4 < e; j += 8) {
    int i0 = csr_src[j], i1 = csr_src[j + 4];
    size_t b0 = (size_t)i0 * 32 + c * 2;
    size_t b1 = (size_t)i1 * 32 + c * 2;
    float4 v0x = hp[b0], v0y = hp[b0 + 1];
    float4 v1x = hp[b1], v1y = hp[b1 + 1];
    if (AGGR == 1) {
      a0x = op_max(a0x, v0x); a0y = op_max(a0y, v0y);
      a1x = op_max(a1x, v1x); a1y = op_max(a1y, v1y);
    } else {
      a0x = op_add(a0x, v0x); a0y = op_add(a0y, v0y);
      a1x = op_add(a1x, v1x); a1y = op_add(a1y, v1y);
    }
  }
  for (; j < e; j += 4) {
    size_t b0 = (size_t)csr_src[j] * 32 + c * 2;
    float4 v0x = hp[b0], v0y = hp[b0 + 1];
    if (AGGR == 1) { a0x = op_max(a0x, v0x); a0y = op_max(a0y, v0y); }
    else           { a0x = op_add(a0x, v0x); a0y = op_add(a0y, v0y); }
  }
  float4 rx, ry;
  if (AGGR == 1) { rx = op_max(a0x, a1x); ry = op_max(a0y, a1y); }
  else           { rx = op_add(a0x, a1x); ry = op_add(a0y, a1y); }
  // reduce across the 4 slots (xor 16, then 32)
  #pragma unroll
  for (int off = 16; off <= 32; off <<= 1) {
    float4 ox, oy;
    ox.x = __shfl_xor(rx.x, off, 64); ox.y = __shfl_xor(rx.y, off, 64);
    ox.z = __shfl_xor(rx.z, off, 64); ox.w = __shfl_xor(rx.w, off, 64);
    oy.x = __shfl_xor(ry.x, off, 64); oy.y = __shfl_xor(ry.y, off, 64);
    oy.z = __shfl_xor(ry.z, off, 64); oy.w = __shfl_xor(ry.w, off, 64);
    if (AGGR == 1) { rx = op_max(rx, ox); ry = op_max(ry, oy); }
    else           { rx = op_add(rx, ox); ry = op_add(ry, oy); }
  }
  if (slot == 0) {
    if (AGGR == 1) {
      if (e == s) { rx = make_float4(0.f,0.f,0.f,0.f); ry = rx; }
    } else if (AGGR == 2) {
      float inv = 1.0f / fmaxf((float)(e - s), 1.0f);
      rx.x *= inv; rx.y *= inv; rx.z *= inv; rx.w *= inv;
      ry.x *= inv; ry.y *= inv; ry.z *= inv; ry.w *= inv;
    }
    float4* op = (float4*)agg + (size_t)node * 32 + c * 2;
    op[0] = rx;
    op[1] = ry;
  }
}

// ---------------- MFMA GEMM (bf16x3 split): out = relu(A1@W1 [+ A2@W2] + bias) ----------------

#define GBM 128

__global__ __launch_bounds__(256) void k_gemm(
    const float* __restrict__ A1, const ushort_t* __restrict__ Wh1, const ushort_t* __restrict__ Wl1,
    const float* __restrict__ A2, const ushort_t* __restrict__ Wh2, const ushort_t* __restrict__ Wl2,
    const float* __restrict__ bias, float* __restrict__ out, int M, int has2) {
  __shared__ ushort_t Ah[128 * 40];
  __shared__ ushort_t Al[128 * 40];
  __shared__ ushort_t Bh[128 * 40];
  __shared__ ushort_t Bl[128 * 40];
  int t = threadIdx.x;
  int lane = t & 63, wid = t >> 6;
  int wr = wid >> 1, wc = wid & 1;
  int l15 = lane & 15, kg = lane >> 4;
  int row0 = blockIdx.x * GBM;

  f32x4 acc[4][4] = {};

  int nmat = has2 ? 2 : 1;
  for (int mat = 0; mat < nmat; ++mat) {
    const float* __restrict__ A = mat ? A2 : A1;
    const ushort_t* __restrict__ Wh = mat ? Wh2 : Wh1;
    const ushort_t* __restrict__ Wl = mat ? Wl2 : Wl1;
    for (int kt = 0; kt < 4; ++kt) {
      __syncthreads();
      {
        int r = t >> 3, cq = t & 7;
        #pragma unroll
        for (int rr = 0; rr < 4; ++rr) {
          int row = r + rr * 32;
          int grow = row0 + row;
          float4 v = make_float4(0.f, 0.f, 0.f, 0.f);
          if (grow < M) v = *(const float4*)&A[(size_t)grow * D + kt * 32 + cq * 4];
          unsigned u0 = __float_as_uint(v.x), u1 = __float_as_uint(v.y);
          unsigned u2 = __float_as_uint(v.z), u3 = __float_as_uint(v.w);
          unsigned h01 = (u0 >> 16) | (u1 & 0xffff0000u);
          unsigned h23 = (u2 >> 16) | (u3 & 0xffff0000u);
          float f0 = v.x - __uint_as_float(u0 & 0xffff0000u);
          float f1 = v.y - __uint_as_float(u1 & 0xffff0000u);
          float f2 = v.z - __uint_as_float(u2 & 0xffff0000u);
          float f3 = v.w - __uint_as_float(u3 & 0xffff0000u);
          unsigned l01 = (__float_as_uint(f0) >> 16) | (__float_as_uint(f1) & 0xffff0000u);
          unsigned l23 = (__float_as_uint(f2) >> 16) | (__float_as_uint(f3) & 0xffff0000u);
          *(uint2*)&Ah[row * 40 + cq * 4] = make_uint2(h01, h23);
          *(uint2*)&Al[row * 40 + cq * 4] = make_uint2(l01, l23);
        }
      }
      {
        int c = t >> 1, q = t & 1;
        const ushort_t* sh = Wh + (size_t)kt * 4096 + t * 16;
        const ushort_t* sl = Wl + (size_t)kt * 4096 + t * 16;
        uint4 a0 = *(const uint4*)sh;
        uint4 a1 = *(const uint4*)(sh + 8);
        uint4 b0 = *(const uint4*)sl;
        uint4 b1 = *(const uint4*)(sl + 8);
        *(uint4*)&Bh[c * 40 + q * 16]     = a0;
        *(uint4*)&Bh[c * 40 + q * 16 + 8] = a1;
        *(uint4*)&Bl[c * 40 + q * 16]     = b0;
        *(uint4*)&Bl[c * 40 + q * 16 + 8] = b1;
      }
      __syncthreads();
      short8 ah[4], al[4], bh[4], bl[4];
      #pragma unroll
      for (int m = 0; m < 4; ++m) {
        int row = wr * 64 + m * 16 + l15;
        ah[m] = *(const short8*)&Ah[row * 40 + kg * 8];
        al[m] = *(const short8*)&Al[row * 40 + kg * 8];
      }
      #pragma unroll
      for (int n = 0; n < 4; ++n) {
        int col = wc * 64 + n * 16 + l15;
        bh[n] = *(const short8*)&Bh[col * 40 + kg * 8];
        bl[n] = *(const short8*)&Bl[col * 40 + kg * 8];
      }
      #pragma unroll
      for (int m = 0; m < 4; ++m)
        #pragma unroll
        for (int n = 0; n < 4; ++n) {
          acc[m][n] = __builtin_amdgcn_mfma_f32_16x16x32_bf16(ah[m], bh[n], acc[m][n], 0, 0, 0);
          acc[m][n] = __builtin_amdgcn_mfma_f32_16x16x32_bf16(ah[m], bl[n], acc[m][n], 0, 0, 0);
          acc[m][n] = __builtin_amdgcn_mfma_f32_16x16x32_bf16(al[m], bh[n], acc[m][n], 0, 0, 0);
        }
    }
  }
  int crow = kg * 4;
  #pragma unroll
  for (int n = 0; n < 4; ++n) {
    int col = wc * 64 + n * 16 + l15;
    float b = bias[col];
    #pragma unroll
    for (int m = 0; m < 4; ++m) {
      int rbase = row0 + wr * 64 + m * 16 + crow;
      #pragma unroll
      for (int q = 0; q < 4; ++q) {
        int grow = rbase + q;
        if (grow < M) out[(size_t)grow * D + col] = fmaxf(acc[m][n][q] + b, 0.f);
      }
    }
  }
}

// ---------------- Head: out[n,2] = h @ w2 + b2 ----------------

__global__ __launch_bounds__(256) void k_head(const float* __restrict__ h,
                                              const float* __restrict__ w2,
                                              const float* __restrict__ b2,
                                              float* __restrict__ out, int n) {
  int lane = threadIdx.x & 63;
  int node = blockIdx.x * 4 + (threadIdx.x >> 6);
  if (node >= n) return;
  float2 v = ((const float2*)h)[(size_t)node * 64 + lane];
  float4 w = *(const float4*)&w2[lane * 4];
  float p0 = v.x * w.x + v.y * w.z;
  float p1 = v.x * w.y + v.y * w.w;
  #pragma unroll
  for (int off = 32; off; off >>= 1) {
    p0 += __shfl_xor(p0, off, 64);
    p1 += __shfl_xor(p1, off, 64);
  }
  if (lane == 0)
    ((float2*)out)[node] = make_float2(p0 + b2[0], p1 + b2[1]);
}

// ---------------- Launch ----------------

extern "C" void kernel_launch(void* const* d_in, const int* in_sizes, int n_in,
                              void* d_out, int out_size, void* d_ws, size_t ws_size,
                              hipStream_t stream) {
  const float* x   = (const float*)d_in[0];
  const int*   ei  = (const int*)d_in[1];
  const float* w_l = (const float*)d_in[2];
  const float* b_l = (const float*)d_in[3];
  const float* w_r = (const float*)d_in[4];
  const float* w1  = (const float*)d_in[5];
  const float* b1  = (const float*)d_in[6];
  const float* w2  = (const float*)d_in[7];
  const float* b2  = (const float*)d_in[8];
  float* out = (float*)d_out;

  const int* src = ei;        // edge_index[0]
  const int* dst = ei + NE;   // edge_index[1]

  char* ws = (char*)d_ws;
  size_t SZ = (size_t)NN * D * sizeof(float);
  float* bufA = (float*)ws;
  float* bufB = (float*)(ws + SZ);
  int* csr_src   = (int*)(ws + 2 * SZ);
  int* row_start = (int*)(ws + 2 * SZ + (size_t)NE * sizeof(int));
  int* cursor    = row_start + NN + 2;
  int* cnt       = cursor + NN + 2;
  ushort_t* whi  = (ushort_t*)(cnt + NN + 2);
  ushort_t* wlo  = whi + 13 * 16384;

  k_wsplit<<<(6 * 16384 + 255) / 256, 256, 0, stream>>>(w_l, whi, wlo, 6 * 16384);
  k_wsplit<<<(6 * 16384 + 255) / 256, 256, 0, stream>>>(w_r, whi + 6 * 16384, wlo + 6 * 16384, 6 * 16384);
  k_wsplit<<<(16384 + 255) / 256, 256, 0, stream>>>(w1, whi + 12 * 16384, wlo + 12 * 16384, 16384);

  hipMemsetAsync(cnt, 0, NN * sizeof(int), stream);
  k_hist<<<(NE + 255) / 256, 256, 0, stream>>>(dst, cnt, NE);
  k_scan<<<1, 1024, 0, stream>>>(cnt, row_start, cursor, NN);
  k_scatter<<<(NE / 4 + 255) / 256, 256, 0, stream>>>(src, dst, cursor, csr_src, NE);

  const int agg_grid  = (NN + 3) / 4;
  const int gemm_grid = (NN + GBM - 1) / GBM;

  const float* h = x;
  float* bufs[2] = {bufA, bufB};
  for (int i = 0; i < 6; ++i) {
    float* aggb = bufs[i & 1];
    switch (i % 3) {
      case 0: k_aggregate<0><<<agg_grid, 256, 0, stream>>>(h, csr_src, row_start, aggb, NN); break;
      case 1: k_aggregate<1><<<agg_grid, 256, 0, stream>>>(h, csr_src, row_start, aggb, NN); break;
      case 2: k_aggregate<2><<<agg_grid, 256, 0, stream>>>(h, csr_src, row_start, aggb, NN); break;
    }
    k_gemm<<<gemm_grid, 256, 0, stream>>>(aggb, whi + (size_t)i * 16384, wlo + (size_t)i * 16384,
                                          h,    whi + (size_t)(6 + i) * 16384, wlo + (size_t)(6 + i) * 16384,
                                          b_l + (size_t)i * D, aggb, NN, 1);
    h = aggb;
  }
  k_gemm<<<gemm_grid, 256, 0, stream>>>(h, whi + (size_t)12 * 16384, wlo + (size_t)12 * 16384,
                                        h, nullptr, nullptr, b1, bufA, NN, 0);
  k_head<<<agg_grid, 256, 0, stream>>>(bufA, w2, b2, out, NN);
}

// Round 4
// 468.164 us; speedup vs baseline: 1.9042x; 1.3766x over previous
//
#include <hip/hip_runtime.h>

#define NN 50000
#define NE 800000
#define D 128

typedef unsigned short ushort_t;
typedef __attribute__((ext_vector_type(8))) short short8;
typedef __attribute__((ext_vector_type(4))) float f32x4;
typedef __attribute__((ext_vector_type(8))) _Float16 half8;
typedef __attribute__((ext_vector_type(2))) _Float16 half2v;

// ---------------- CSR build ----------------

__global__ void k_hist(const int* __restrict__ dst, int* __restrict__ cnt, int e) {
  int i = blockIdx.x * blockDim.x + threadIdx.x;
  if (i < e) atomicAdd(&cnt[dst[i]], 1);
}

// 1024 threads, 4 elems/thread/iter. Writes row_start AND cursor (= copy).
__global__ __launch_bounds__(1024) void k_scan(const int* __restrict__ cnt,
                                               int* __restrict__ row_start,
                                               int* __restrict__ cursor, int n) {
  __shared__ int wsum[16];
  __shared__ int carry_s;
  int t = threadIdx.x;
  int lane = t & 63, wid = t >> 6;
  if (t == 0) carry_s = 0;
  __syncthreads();
  for (int base = 0; base < n; base += 4096) {
    int i = base + t * 4;
    int4 v = make_int4(0, 0, 0, 0);
    if (i + 3 < n) v = *(const int4*)&cnt[i];
    else if (i < n) {
      v.x = cnt[i];
      if (i + 1 < n) v.y = cnt[i + 1];
      if (i + 2 < n) v.z = cnt[i + 2];
    }
    int tot = v.x + v.y + v.z + v.w;
    int x = tot;
    #pragma unroll
    for (int off = 1; off < 64; off <<= 1) {
      int y = __shfl_up(x, off, 64);
      if (lane >= off) x += y;
    }
    if (lane == 63) wsum[wid] = x;
    __syncthreads();
    if (wid == 0) {
      int w = (lane < 16) ? wsum[lane] : 0;
      #pragma unroll
      for (int off = 1; off < 16; off <<= 1) {
        int y = __shfl_up(w, off, 64);
        if (lane >= off) w += y;
      }
      if (lane < 16) wsum[lane] = w;
    }
    __syncthreads();
    int off0 = carry_s + (wid ? wsum[wid - 1] : 0) + (x - tot);
    int4 o;
    o.x = off0;
    o.y = off0 + v.x;
    o.z = off0 + v.x + v.y;
    o.w = off0 + v.x + v.y + v.z;
    if (i + 3 < n) {
      *(int4*)&row_start[i] = o;
      *(int4*)&cursor[i] = o;
    } else if (i < n) {
      row_start[i] = o.x; cursor[i] = o.x;
      if (i + 1 < n) { row_start[i + 1] = o.y; cursor[i + 1] = o.y; }
      if (i + 2 < n) { row_start[i + 2] = o.z; cursor[i + 2] = o.z; }
    }
    __syncthreads();
    if (t == 0) carry_s += wsum[15];
    __syncthreads();
  }
  if (t == 0) row_start[n] = carry_s;
}

// 4 edges per thread, independent atomic->write chains. NE % 4 == 0.
__global__ __launch_bounds__(256) void k_scatter(const int* __restrict__ src,
                                                 const int* __restrict__ dst,
                                                 int* __restrict__ cursor,
                                                 int* __restrict__ csr_src, int e) {
  int i = (blockIdx.x * 256 + threadIdx.x) * 4;
  if (i >= e) return;
  int4 s4 = *(const int4*)&src[i];
  int4 d4 = *(const int4*)&dst[i];
  int p0 = atomicAdd(&cursor[d4.x], 1);
  int p1 = atomicAdd(&cursor[d4.y], 1);
  int p2 = atomicAdd(&cursor[d4.z], 1);
  int p3 = atomicAdd(&cursor[d4.w], 1);
  csr_src[p0] = s4.x;
  csr_src[p1] = s4.y;
  csr_src[p2] = s4.z;
  csr_src[p3] = s4.w;
}

// ---------------- fp32 x -> fp16 ----------------

__global__ __launch_bounds__(256) void k_tofp16(const float* __restrict__ in,
                                                _Float16* __restrict__ out, int n8) {
  int i = blockIdx.x * 256 + threadIdx.x;
  if (i >= n8) return;
  float4 a = ((const float4*)in)[i * 2];
  float4 b = ((const float4*)in)[i * 2 + 1];
  half8 o;
  o[0] = (_Float16)a.x; o[1] = (_Float16)a.y; o[2] = (_Float16)a.z; o[3] = (_Float16)a.w;
  o[4] = (_Float16)b.x; o[5] = (_Float16)b.y; o[6] = (_Float16)b.z; o[7] = (_Float16)b.w;
  ((half8*)out)[i] = o;
}

// ---------------- Weight pre-split: fp32 [mat][k][c] -> bf16 hi/lo planes ----------------
// Plane layout (per mat, 16384 elems): [kt=k>>5][c][k&31]

__global__ void k_wsplit(const float* __restrict__ W, ushort_t* __restrict__ hi,
                         ushort_t* __restrict__ lo, int total) {
  int idx = blockIdx.x * 256 + threadIdx.x;
  if (idx >= total) return;
  int mat = idx >> 14, rem = idx & 16383;
  int k = rem >> 7, c = rem & 127;
  float f = W[idx];
  unsigned u = __float_as_uint(f);
  float lf = f - __uint_as_float(u & 0xffff0000u);
  size_t dst = ((size_t)mat << 14) + (size_t)(k >> 5) * 4096 + c * 32 + (k & 31);
  hi[dst] = (ushort_t)(u >> 16);
  lo[dst] = (ushort_t)(__float_as_uint(lf) >> 16);
}

// ---------------- Aggregation: one wave per node, 16 lanes per edge, fp16 rows ----------------
// AGGR: 0 = sum, 1 = max, 2 = mean. Row = 256 B = 16 half8; lane owns 8 cols.

__device__ __forceinline__ float4 op_add(float4 a, float4 v) {
  a.x += v.x; a.y += v.y; a.z += v.z; a.w += v.w; return a;
}
__device__ __forceinline__ float4 op_max(float4 a, float4 v) {
  a.x = fmaxf(a.x, v.x); a.y = fmaxf(a.y, v.y);
  a.z = fmaxf(a.z, v.z); a.w = fmaxf(a.w, v.w); return a;
}
__device__ __forceinline__ void h8_to_f(half8 v, float4& x, float4& y) {
  x.x = (float)v[0]; x.y = (float)v[1]; x.z = (float)v[2]; x.w = (float)v[3];
  y.x = (float)v[4]; y.y = (float)v[5]; y.z = (float)v[6]; y.w = (float)v[7];
}

template <int AGGR>
__global__ __launch_bounds__(256) void k_aggregate(const _Float16* __restrict__ h,
                                                   const int* __restrict__ csr_src,
                                                   const int* __restrict__ row_start,
                                                   _Float16* __restrict__ agg, int n) {
  int lane = threadIdx.x & 63;
  int node = blockIdx.x * 4 + (threadIdx.x >> 6);
  if (node >= n) return;
  int slot = lane >> 4, c = lane & 15;
  const half8* __restrict__ hp = (const half8*)h;
  int s = row_start[node], e = row_start[node + 1];
  float4 init;
  if (AGGR == 1) init = make_float4(-INFINITY, -INFINITY, -INFINITY, -INFINITY);
  else           init = make_float4(0.f, 0.f, 0.f, 0.f);
  float4 a0x = init, a0y = init, a1x = init, a1y = init;
  int j = s + slot;
  for (; j + 4 < e; j += 8) {
    int i0 = csr_src[j], i1 = csr_src[j + 4];
    half8 v0 = hp[(size_t)i0 * 16 + c];
    half8 v1 = hp[(size_t)i1 * 16 + c];
    float4 v0x, v0y, v1x, v1y;
    h8_to_f(v0, v0x, v0y);
    h8_to_f(v1, v1x, v1y);
    if (AGGR == 1) {
      a0x = op_max(a0x, v0x); a0y = op_max(a0y, v0y);
      a1x = op_max(a1x, v1x); a1y = op_max(a1y, v1y);
    } else {
      a0x = op_add(a0x, v0x); a0y = op_add(a0y, v0y);
      a1x = op_add(a1x, v1x); a1y = op_add(a1y, v1y);
    }
  }
  for (; j < e; j += 4) {
    half8 v0 = hp[(size_t)csr_src[j] * 16 + c];
    float4 v0x, v0y;
    h8_to_f(v0, v0x, v0y);
    if (AGGR == 1) { a0x = op_max(a0x, v0x); a0y = op_max(a0y, v0y); }
    else           { a0x = op_add(a0x, v0x); a0y = op_add(a0y, v0y); }
  }
  float4 rx, ry;
  if (AGGR == 1) { rx = op_max(a0x, a1x); ry = op_max(a0y, a1y); }
  else           { rx = op_add(a0x, a1x); ry = op_add(a0y, a1y); }
  #pragma unroll
  for (int off = 16; off <= 32; off <<= 1) {
    float4 ox, oy;
    ox.x = __shfl_xor(rx.x, off, 64); ox.y = __shfl_xor(rx.y, off, 64);
    ox.z = __shfl_xor(rx.z, off, 64); ox.w = __shfl_xor(rx.w, off, 64);
    oy.x = __shfl_xor(ry.x, off, 64); oy.y = __shfl_xor(ry.y, off, 64);
    oy.z = __shfl_xor(ry.z, off, 64); oy.w = __shfl_xor(ry.w, off, 64);
    if (AGGR == 1) { rx = op_max(rx, ox); ry = op_max(ry, oy); }
    else           { rx = op_add(rx, ox); ry = op_add(ry, oy); }
  }
  if (slot == 0) {
    if (AGGR == 1) {
      if (e == s) { rx = make_float4(0.f,0.f,0.f,0.f); ry = rx; }
    } else if (AGGR == 2) {
      float inv = 1.0f / fmaxf((float)(e - s), 1.0f);
      rx.x *= inv; rx.y *= inv; rx.z *= inv; rx.w *= inv;
      ry.x *= inv; ry.y *= inv; ry.z *= inv; ry.w *= inv;
    }
    half8 o;
    o[0] = (_Float16)rx.x; o[1] = (_Float16)rx.y; o[2] = (_Float16)rx.z; o[3] = (_Float16)rx.w;
    o[4] = (_Float16)ry.x; o[5] = (_Float16)ry.y; o[6] = (_Float16)ry.z; o[7] = (_Float16)ry.w;
    ((half8*)agg)[(size_t)node * 16 + c] = o;
  }
}

// ---------------- MFMA GEMM (bf16x3 split, fp16 A): out = relu(A1@W1 [+ A2@W2] + bias) ----------------
// A: [M,128] fp16. W planes: pre-split bf16 hi/lo [kt][c][32]. out fp16, may alias A1.

#define GBM 64

__global__ __launch_bounds__(256) void k_gemm(
    const _Float16* __restrict__ A1, const ushort_t* __restrict__ Wh1, const ushort_t* __restrict__ Wl1,
    const _Float16* __restrict__ A2, const ushort_t* __restrict__ Wh2, const ushort_t* __restrict__ Wl2,
    const float* __restrict__ bias, _Float16* __restrict__ out, int M, int has2) {
  __shared__ ushort_t Ah[GBM * 40];
  __shared__ ushort_t Al[GBM * 40];
  __shared__ ushort_t Bh[128 * 40];
  __shared__ ushort_t Bl[128 * 40];
  int t = threadIdx.x;
  int lane = t & 63, wid = t >> 6;
  int wr = wid >> 1, wc = wid & 1;      // wave tile: 32 rows x 64 cols
  int l15 = lane & 15, kg = lane >> 4;
  int row0 = blockIdx.x * GBM;

  f32x4 acc[2][4] = {};

  int nmat = has2 ? 2 : 1;
  for (int mat = 0; mat < nmat; ++mat) {
    const _Float16* __restrict__ A = mat ? A2 : A1;
    const ushort_t* __restrict__ Wh = mat ? Wh2 : Wh1;
    const ushort_t* __restrict__ Wl = mat ? Wl2 : Wl1;
    for (int kt = 0; kt < 4; ++kt) {
      __syncthreads();
      // stage A tile (64 rows x 32 k) fp16 -> bf16 hi/lo; one pass, 8 halves/thread
      {
        int r = t >> 2, cq = t & 3;
        int grow = row0 + r;
        half8 v = {};
        if (grow < M) v = *(const half8*)&A[(size_t)grow * D + kt * 32 + cq * 8];
        unsigned hw[8], lw[8];
        #pragma unroll
        for (int eidx = 0; eidx < 8; ++eidx) {
          float f = (float)v[eidx];
          unsigned u = __float_as_uint(f);
          float lf = f - __uint_as_float(u & 0xffff0000u);
          hw[eidx] = u >> 16;
          lw[eidx] = __float_as_uint(lf) >> 16;
        }
        uint4 hv = make_uint4(hw[0] | (hw[1] << 16), hw[2] | (hw[3] << 16),
                              hw[4] | (hw[5] << 16), hw[6] | (hw[7] << 16));
        uint4 lv = make_uint4(lw[0] | (lw[1] << 16), lw[2] | (lw[3] << 16),
                              lw[4] | (lw[5] << 16), lw[6] | (lw[7] << 16));
        *(uint4*)&Ah[r * 40 + cq * 8] = hv;
        *(uint4*)&Al[r * 40 + cq * 8] = lv;
      }
      // stage W tile (128 c x 32 k) from pre-split planes
      {
        int c = t >> 1, q = t & 1;
        const ushort_t* sh = Wh + (size_t)kt * 4096 + t * 16;
        const ushort_t* sl = Wl + (size_t)kt * 4096 + t * 16;
        uint4 a0 = *(const uint4*)sh;
        uint4 a1 = *(const uint4*)(sh + 8);
        uint4 b0 = *(const uint4*)sl;
        uint4 b1 = *(const uint4*)(sl + 8);
        *(uint4*)&Bh[c * 40 + q * 16]     = a0;
        *(uint4*)&Bh[c * 40 + q * 16 + 8] = a1;
        *(uint4*)&Bl[c * 40 + q * 16]     = b0;
        *(uint4*)&Bl[c * 40 + q * 16 + 8] = b1;
      }
      __syncthreads();
      short8 ah[2], al[2], bh[4], bl[4];
      #pragma unroll
      for (int m = 0; m < 2; ++m) {
        int row = wr * 32 + m * 16 + l15;
        ah[m] = *(const short8*)&Ah[row * 40 + kg * 8];
        al[m] = *(const short8*)&Al[row * 40 + kg * 8];
      }
      #pragma unroll
      for (int n = 0; n < 4; ++n) {
        int col = wc * 64 + n * 16 + l15;
        bh[n] = *(const short8*)&Bh[col * 40 + kg * 8];
        bl[n] = *(const short8*)&Bl[col * 40 + kg * 8];
      }
      #pragma unroll
      for (int m = 0; m < 2; ++m)
        #pragma unroll
        for (int n = 0; n < 4; ++n) {
          acc[m][n] = __builtin_amdgcn_mfma_f32_16x16x32_bf16(ah[m], bh[n], acc[m][n], 0, 0, 0);
          acc[m][n] = __builtin_amdgcn_mfma_f32_16x16x32_bf16(ah[m], bl[n], acc[m][n], 0, 0, 0);
          acc[m][n] = __builtin_amdgcn_mfma_f32_16x16x32_bf16(al[m], bh[n], acc[m][n], 0, 0, 0);
        }
    }
  }
  int crow = kg * 4;
  #pragma unroll
  for (int n = 0; n < 4; ++n) {
    int col = wc * 64 + n * 16 + l15;
    float b = bias[col];
    #pragma unroll
    for (int m = 0; m < 2; ++m) {
      int rbase = row0 + wr * 32 + m * 16 + crow;
      #pragma unroll
      for (int q = 0; q < 4; ++q) {
        int grow = rbase + q;
        if (grow < M)
          out[(size_t)grow * D + col] = (_Float16)fmaxf(acc[m][n][q] + b, 0.f);
      }
    }
  }
}

// ---------------- Head: out[n,2] = h @ w2 + b2 ----------------

__global__ __launch_bounds__(256) void k_head(const _Float16* __restrict__ h,
                                              const float* __restrict__ w2,
                                              const float* __restrict__ b2,
                                              float* __restrict__ out, int n) {
  int lane = threadIdx.x & 63;
  int node = blockIdx.x * 4 + (threadIdx.x >> 6);
  if (node >= n) return;
  half2v v = *(const half2v*)&h[(size_t)node * D + lane * 2];
  float v0 = (float)v[0], v1 = (float)v[1];
  float4 w = *(const float4*)&w2[lane * 4];
  float p0 = v0 * w.x + v1 * w.z;
  float p1 = v0 * w.y + v1 * w.w;
  #pragma unroll
  for (int off = 32; off; off >>= 1) {
    p0 += __shfl_xor(p0, off, 64);
    p1 += __shfl_xor(p1, off, 64);
  }
  if (lane == 0)
    ((float2*)out)[node] = make_float2(p0 + b2[0], p1 + b2[1]);
}

// ---------------- Launch ----------------

extern "C" void kernel_launch(void* const* d_in, const int* in_sizes, int n_in,
                              void* d_out, int out_size, void* d_ws, size_t ws_size,
                              hipStream_t stream) {
  const float* x   = (const float*)d_in[0];
  const int*   ei  = (const int*)d_in[1];
  const float* w_l = (const float*)d_in[2];
  const float* b_l = (const float*)d_in[3];
  const float* w_r = (const float*)d_in[4];
  const float* w1  = (const float*)d_in[5];
  const float* b1  = (const float*)d_in[6];
  const float* w2  = (const float*)d_in[7];
  const float* b2  = (const float*)d_in[8];
  float* out = (float*)d_out;

  const int* src = ei;        // edge_index[0]
  const int* dst = ei + NE;   // edge_index[1]

  char* ws = (char*)d_ws;
  size_t SZH = (size_t)NN * D * sizeof(_Float16);   // 12.8 MB
  _Float16* bufX = (_Float16*)ws;
  _Float16* bufA = (_Float16*)(ws + SZH);
  _Float16* bufB = (_Float16*)(ws + 2 * SZH);
  int* csr_src   = (int*)(ws + 3 * SZH);
  int* row_start = (int*)(ws + 3 * SZH + (size_t)NE * sizeof(int));
  int* cursor    = row_start + NN + 2;
  int* cnt       = cursor + NN + 2;
  ushort_t* whi  = (ushort_t*)(cnt + NN + 2);
  ushort_t* wlo  = whi + 13 * 16384;

  k_wsplit<<<(6 * 16384 + 255) / 256, 256, 0, stream>>>(w_l, whi, wlo, 6 * 16384);
  k_wsplit<<<(6 * 16384 + 255) / 256, 256, 0, stream>>>(w_r, whi + 6 * 16384, wlo + 6 * 16384, 6 * 16384);
  k_wsplit<<<(16384 + 255) / 256, 256, 0, stream>>>(w1, whi + 12 * 16384, wlo + 12 * 16384, 16384);
  k_tofp16<<<(NN * D / 8 + 255) / 256, 256, 0, stream>>>(x, bufX, NN * D / 8);

  hipMemsetAsync(cnt, 0, NN * sizeof(int), stream);
  k_hist<<<(NE + 255) / 256, 256, 0, stream>>>(dst, cnt, NE);
  k_scan<<<1, 1024, 0, stream>>>(cnt, row_start, cursor, NN);
  k_scatter<<<(NE / 4 + 255) / 256, 256, 0, stream>>>(src, dst, cursor, csr_src, NE);

  const int agg_grid  = (NN + 3) / 4;
  const int gemm_grid = (NN + GBM - 1) / GBM;

  const _Float16* h = bufX;
  _Float16* bufs[2] = {bufA, bufB};
  for (int i = 0; i < 6; ++i) {
    _Float16* aggb = bufs[i & 1];
    switch (i % 3) {
      case 0: k_aggregate<0><<<agg_grid, 256, 0, stream>>>(h, csr_src, row_start, aggb, NN); break;
      case 1: k_aggregate<1><<<agg_grid, 256, 0, stream>>>(h, csr_src, row_start, aggb, NN); break;
      case 2: k_aggregate<2><<<agg_grid, 256, 0, stream>>>(h, csr_src, row_start, aggb, NN); break;
    }
    k_gemm<<<gemm_grid, 256, 0, stream>>>(aggb, whi + (size_t)i * 16384, wlo + (size_t)i * 16384,
                                          h,    whi + (size_t)(6 + i) * 16384, wlo + (size_t)(6 + i) * 16384,
                                          b_l + (size_t)i * D, aggb, NN, 1);
    h = aggb;
  }
  // h == bufB after layer 5
  k_gemm<<<gemm_grid, 256, 0, stream>>>(h, whi + (size_t)12 * 16384, wlo + (size_t)12 * 16384,
                                        h, nullptr, nullptr, b1, bufA, NN, 0);
  k_head<<<agg_grid, 256, 0, stream>>>(bufA, w2, b2, out, NN);
}